// Round 11
// baseline (285.733 us; speedup 1.0000x reference)
//
#include <hip/hip_runtime.h>

// ---------------------------------------------------------------------------
// VanillaSFNN fully fused, contiguous-x edition.
//   k0 wprep : W_h f32 -> split bf16 hi/lo, BK=32 fragment tiles (22 x 8KB)
//   k1 fused : 256 blocks (1/batch) x 512 thr (8 waves).
//     - W entirely in VGPRs: wave (wm,wn) preloads its n-frag for all 22
//       k-tiles (176 VGPRs) -> vmcnt stream is PURE x.
//     - x streamed in address order: pieces = 32 rows x 1408B k-half,
//       45KB each, XOR-swizzled via pre-swizzled source, glds ring-3,
//       uniform 6 glds/thread/piece (dummy pad for waves 4-7), vmcnt(12).
//     - per 32-row group: k order = half0 kt0..10, half1 kt0..10 ==
//       rounds 4-10's 22-step order -> currents bitwise identical.
//     - exact sequential LIF from LDS tile (no burn-in), masks in LDS.
//     - readout scan (r10's proven 12us) from LDS masks.
// ---------------------------------------------------------------------------

typedef float  f32x4  __attribute__((ext_vector_type(4)));
typedef short  short8 __attribute__((ext_vector_type(8)));
typedef unsigned long long ull;

#define B_   256
#define T_   1000
#define K_   700
#define H_   64
#define O_   20
#define NCH  200         // readout chunks
#define TCH  5

// LDS map (bytes)
#define L_XBUF   45056                  // 2816 chunks x 16B
#define L_SCR    135168                 // 1KB dummy-glds scratch
#define L_CURT   136192                 // 32*64*4 = 8KB
#define L_MASK   144384                 // 1000*8  = 8KB
#define L_TOT    152384

// ---------------------------------------------------------------------------
// k0: W_h -> split-bf16 fragments, BK=32 tiles. Tile kt (4096 shorts):
// hi 256 slots x 8, then lo. slot = nf*64+lane: h = nf*16+(lane&15),
// k = kt*32 + ((lane>>4)&3)*8 + j. Zero-pad k >= 700.
// ---------------------------------------------------------------------------
__global__ void wprep(const float* __restrict__ Wh, unsigned short* __restrict__ wfrag) {
    int e = blockIdx.x * 256 + threadIdx.x;          // 22*256 = 5632 exact
    int kt   = e >> 8;
    int rem  = e & 255;
    int nf   = rem >> 6;
    int lane = rem & 63;
    int h     = nf * 16 + (lane & 15);
    int kbase = kt * 32 + ((lane >> 4) & 3) * 8;
    unsigned short* dh = wfrag + (size_t)kt * 4096 + (nf * 64 + lane) * 8;
    unsigned short* dl = dh + 2048;
#pragma unroll
    for (int j = 0; j < 8; ++j) {
        int k = kbase + j;
        float v = (k < K_) ? Wh[(size_t)h * K_ + k] : 0.0f;
        unsigned u  = __builtin_bit_cast(unsigned, v);
        float    fh = __builtin_bit_cast(float, u & 0xffff0000u);
        float    r  = v - fh;
        dh[j] = (unsigned short)(u >> 16);
        dl[j] = (unsigned short)(__builtin_bit_cast(unsigned, r) >> 16);
    }
}

// ---------------------------------------------------------------------------
__device__ __forceinline__ void glds16(const void* src, void* lds) {
    __builtin_amdgcn_global_load_lds(
        (const __attribute__((address_space(1))) void*)src,
        (__attribute__((address_space(3))) void*)lds, 16, 0, 0);
}

__device__ __forceinline__ void splitpair(f32x4 p0, f32x4 p1, short8& hi, short8& lo) {
#pragma unroll
    for (int j = 0; j < 4; ++j) {
        {
            unsigned u  = __builtin_bit_cast(unsigned, p0[j]);
            float    fh = __builtin_bit_cast(float, u & 0xffff0000u);
            float    r  = p0[j] - fh;
            hi[j] = (short)(u >> 16);
            lo[j] = (short)(__builtin_bit_cast(unsigned, r) >> 16);
        }
        {
            unsigned u  = __builtin_bit_cast(unsigned, p1[j]);
            float    fh = __builtin_bit_cast(float, u & 0xffff0000u);
            float    r  = p1[j] - fh;
            hi[j + 4] = (short)(u >> 16);
            lo[j + 4] = (short)(__builtin_bit_cast(unsigned, r) >> 16);
        }
    }
}

// stage one x piece: group g, k-half h -> 2816 chunks into dstbase.
// Uniform 6 glds per thread (waves 4-7: 5 real + 1 dummy into scratch).
__device__ __forceinline__ void stage_piece(const char* xb, int g, int h,
                                            char* dstbase, char* scratch, int wid,
                                            const int (&pr)[6], const int (&pco0)[6],
                                            const int (&pco1)[6], const int (&pd)[6]) {
#pragma unroll
    for (int j = 0; j < 5; ++j) {
        int row = g * 32 + pr[j]; row = row > (T_ - 1) ? (T_ - 1) : row;
        int co  = h ? pco1[j] : pco0[j];
        glds16(xb + (size_t)row * 2800 + h * 1408 + co, dstbase + pd[j]);
    }
    if (wid < 4) {
        int row = g * 32 + pr[5]; row = row > (T_ - 1) ? (T_ - 1) : row;
        int co  = h ? pco1[5] : pco0[5];
        glds16(xb + (size_t)row * 2800 + h * 1408 + co, dstbase + pd[5]);
    } else {
        glds16(xb, scratch);                       // dummy: uniform vmcnt tokens
    }
}

// ---------------------------------------------------------------------------
// fused kernel
// ---------------------------------------------------------------------------
__global__ __launch_bounds__(512, 2) void fused(const float* __restrict__ x,
                                                const unsigned short* __restrict__ wfrag,
                                                const float* __restrict__ b_h,
                                                const float* __restrict__ Wr,
                                                const float* __restrict__ br,
                                                const float* __restrict__ tau,
                                                float* __restrict__ out) {
    __shared__ __align__(16) char L[L_TOT];

    int tid  = threadIdx.x;
    int lane = tid & 63;
    int wid  = tid >> 6;                 // 0..7
    int wm   = wid >> 2;                 // m-frag 0..1
    int wn   = wid & 3;                  // n-frag 0..3
    int b    = blockIdx.x;
    const char* xb = (const char*)x + (size_t)b * T_ * K_ * 4;

    float* curTf = (float*)(L + L_CURT);
    ull*   maskp = (ull*)(L + L_MASK);
    char*  scr   = L + L_SCR;

    // ---- W into VGPRs: wave's n-frag, all 22 k-tiles, hi+lo ----
    short8 wHi[22], wLo[22];
#pragma unroll
    for (int kt = 0; kt < 22; ++kt) {
        const short8* base = (const short8*)(wfrag + (size_t)kt * 4096);
        wHi[kt] = base[wn * 64 + lane];
        wLo[kt] = base[256 + wn * 64 + lane];
    }
    float bh = b_h[wn * 16 + (lane & 15)];
    asm volatile("s_waitcnt vmcnt(0)" ::: "memory");   // clean slate for counting

    // ---- per-thread stage map (constant across pieces) ----
    int pr[6], pco0[6], pco1[6], pd[6];
#pragma unroll
    for (int j = 0; j < 6; ++j) {
        int id, dst;
        if (j < 5) { id = (wid + 8 * j) * 64 + lane; dst = (wid + 8 * j) * 1024; }
        else       { id = 2560 + wid * 64 + lane;    dst = 40960 + wid * 1024; }
        int r  = id / 88;
        int pc = id - r * 88;
        int c  = pc ^ (r & 7);
        pr[j]   = r;
        pco0[j] = c * 16;
        pco1[j] = (c == 87 ? 86 : c) * 16;   // h=1: chunk 87 is pad, avoid OOB
        pd[j]   = dst;
    }

    int rr = wm * 16 + (lane & 15);      // my x row within group
    int rx = rr & 7;
    int g2 = ((lane >> 4) & 3) * 2;      // k-chunk pair base

    f32x4 acc = {0.f, 0.f, 0.f, 0.f};
    float v = 0.0f;                      // exact LIF membrane (lane = neuron)

    // prologue: pieces 0,1,2 into bufs 0,1,2 (18 glds/thread)
    stage_piece(xb, 0, 0, L + 0 * L_XBUF, scr, wid, pr, pco0, pco1, pd);
    stage_piece(xb, 0, 1, L + 1 * L_XBUF, scr, wid, pr, pco0, pco1, pd);
    stage_piece(xb, 1, 0, L + 2 * L_XBUF, scr, wid, pr, pco0, pco1, pd);

#define COMPUTE_HALF(H, BUF)                                                  \
    {                                                                         \
        const char* xr = L + (BUF) * L_XBUF + rr * 1408;                      \
        _Pragma("unroll")                                                     \
        for (int kt = 0; kt < 11; ++kt) {                                     \
            int pcb = kt * 8 + g2;                                            \
            f32x4 p0 = *(const f32x4*)(xr + ((pcb) ^ rx) * 16);               \
            f32x4 p1 = *(const f32x4*)(xr + ((pcb + 1) ^ rx) * 16);           \
            short8 ah, al;                                                    \
            splitpair(p0, p1, ah, al);                                        \
            acc = __builtin_amdgcn_mfma_f32_16x16x32_bf16(ah, wHi[(H)*11+kt], acc, 0, 0, 0); \
            acc = __builtin_amdgcn_mfma_f32_16x16x32_bf16(al, wHi[(H)*11+kt], acc, 0, 0, 0); \
            acc = __builtin_amdgcn_mfma_f32_16x16x32_bf16(ah, wLo[(H)*11+kt], acc, 0, 0, 0); \
        }                                                                     \
    }

#define GROUP_BODY(VMA, VMB, DO_S1, DO_S2)                                    \
    {                                                                         \
        asm volatile("s_waitcnt vmcnt(" VMA ")" ::: "memory");                \
        __builtin_amdgcn_s_barrier();                                         \
        COMPUTE_HALF(0, ba)                                                   \
        asm volatile("s_waitcnt lgkmcnt(0)" ::: "memory");                    \
        __builtin_amdgcn_s_barrier();                                         \
        if (DO_S1) stage_piece(xb, g + 1, 1, L + ba * L_XBUF, scr, wid, pr, pco0, pco1, pd); \
        asm volatile("s_waitcnt vmcnt(" VMB ")" ::: "memory");                \
        __builtin_amdgcn_s_barrier();                                         \
        COMPUTE_HALF(1, bb)                                                   \
        _Pragma("unroll")                                                     \
        for (int j = 0; j < 4; ++j) {                                         \
            int tt = wm * 16 + ((lane >> 4) & 3) * 4 + j;                     \
            curTf[tt * 64 + wn * 16 + (lane & 15)] = acc[j] + bh;             \
        }                                                                     \
        acc = (f32x4){0.f, 0.f, 0.f, 0.f};                                    \
        asm volatile("s_waitcnt lgkmcnt(0)" ::: "memory");                    \
        __builtin_amdgcn_s_barrier();                                         \
        if (DO_S2) stage_piece(xb, g + 2, 0, L + bb * L_XBUF, scr, wid, pr, pco0, pco1, pd); \
        {                                                                     \
            int tcnt = T_ - g * 32; if (tcnt > 32) tcnt = 32;                 \
            for (int j = 0; j < tcnt; ++j) {                                  \
                float c = curTf[j * 64 + lane];                               \
                v = (v + c) * 0.5f;                                           \
                bool sp = (v >= 1.0f);                                        \
                ull m = __ballot(sp);                                         \
                if (tid == 0) maskp[g * 32 + j] = m;                          \
                v = sp ? 0.0f : v;                                            \
            }                                                                 \
        }                                                                     \
    }

    int ba = 0, bb = 1;
    for (int g = 0; g < 31; ++g) {
        GROUP_BODY("12", "12", true, (g < 30))
        ba += 2; if (ba >= 3) ba -= 3;
        bb += 2; if (bb >= 3) bb -= 3;
    }
    {
        int g = 31;
        GROUP_BODY("6", "0", false, false)
    }
#undef GROUP_BODY
#undef COMPUTE_HALF
    __syncthreads();   // masks visible; x-ring region free

    // ---------------- readout (r10's proven structure) ----------------
    char* pool = L;
    float* wt     = (float*)pool;                       // wt[h][o] 5120B
    float (*E)[20]    = (float(*)[20])(pool + 5120);
    float (*Sv)[20]   = (float(*)[20])(pool + 21120);
    float (*pacc)[20] = (float(*)[20])(pool + 37120);
    float* sScale = (float*)(pool + 53120);
    float* sBase  = (float*)(pool + 53216);
    float* sBeta  = (float*)(pool + 53312);
    float (*Pg)[20]   = (float(*)[20])(pool + 53408);
    float (*Sst)[20]  = (float(*)[20])(pool + 54048);
    float (*part)[20] = (float(*)[20])(pool + 54688);
    const ull* smaskL = (const ull*)(L + L_MASK);

    for (int i = tid; i < 1280; i += 512) wt[(i & 63) * 20 + (i >> 6)] = Wr[(size_t)(i >> 6) * 64 + (i & 63)];
    if (tid < 20) {
        float beta = 1.0f / (1.0f + __expf(-tau[tid]));
        sBeta[tid]  = beta;
        sScale[tid] = 1.0f - beta;
        sBase[tid]  = br[tid];
    }
    __syncthreads();

    // phase 1: scanE
    for (int it = tid; it < NCH * 5; it += 512) {
        int o4 = it % 5;
        int c  = it / 5;
        f32x4 beta4  = *(const f32x4*)&sBeta[o4 * 4];
        f32x4 scale4 = *(const f32x4*)&sScale[o4 * 4];
        f32x4 base4  = *(const f32x4*)&sBase[o4 * 4];
        f32x4 vv = {0.f, 0.f, 0.f, 0.f};
        const ull* mp = smaskL + c * TCH;
#pragma unroll
        for (int j = 0; j < TCH; ++j) {
            ull m = mp[j];
            f32x4 a = {0.f, 0.f, 0.f, 0.f};
            while (m) {
                int h = __builtin_ctzll(m);
                m &= (m - 1);
                a += *(const f32x4*)&wt[h * 20 + o4 * 4];
            }
            f32x4 q;
#pragma unroll
            for (int jj = 0; jj < 4; ++jj) q[jj] = scale4[jj] * (base4[jj] + a[jj]);
            vv = beta4 * vv + q;
        }
        *(f32x4*)&E[c][o4 * 4] = vv;
    }
    __syncthreads();

    // phase 2a
    if (tid < 160) {
        int o = tid >> 3, g = tid & 7;
        float beta = sBeta[o];
        float b2 = beta * beta;
        float bp = b2 * b2 * beta;               // beta^5
        float P = 0.0f;
        for (int c = g * 25; c < g * 25 + 25; ++c) P = bp * P + E[c][o];
        Pg[g][o] = P;
    }
    __syncthreads();

    // phase 2b
    if (tid < 20) {
        int o = tid;
        float beta = sBeta[o];
        float b2 = beta * beta;
        float bp = b2 * b2 * beta;
        float bp25 = 1.0f;
#pragma unroll
        for (int i = 0; i < 25; ++i) bp25 *= bp;
        float s = 0.0f;
        for (int g = 0; g < 8; ++g) { Sst[g][o] = s; s = bp25 * s + Pg[g][o]; }
    }
    __syncthreads();

    // phase 2c
    if (tid < 160) {
        int o = tid >> 3, g = tid & 7;
        float beta = sBeta[o];
        float b2 = beta * beta;
        float bp = b2 * b2 * beta;
        float s = Sst[g][o];
        for (int c = g * 25; c < g * 25 + 25; ++c) { Sv[c][o] = s; s = bp * s + E[c][o]; }
    }
    __syncthreads();

    // phase 3: scanSoft
    if (tid < NCH) {
        int c = tid;
        float beta[20], vv[20], ac[20];
#pragma unroll
        for (int o = 0; o < 20; ++o) {
            beta[o] = sBeta[o];
            vv[o]  = Sv[c][o];
            ac[o]  = 0.0f;
        }
        int t0 = c * TCH;
        const ull* mp = smaskL + t0;
#pragma unroll
        for (int j = 0; j < TCH; ++j) {
            int t = t0 + j;
            ull m = mp[j];
            f32x4 a[5];
#pragma unroll
            for (int i = 0; i < 5; ++i) a[i] = (f32x4){0.f, 0.f, 0.f, 0.f};
            while (m) {
                int h = __builtin_ctzll(m);
                m &= (m - 1);
                const f32x4* w4 = (const f32x4*)&wt[h * 20];
#pragma unroll
                for (int i = 0; i < 5; ++i) a[i] += w4[i];
            }
#pragma unroll
            for (int o = 0; o < 20; ++o) {
                float q = sScale[o] * (sBase[o] + a[o >> 2][o & 3]);
                vv[o] = beta[o] * vv[o] + q;
            }
            if (t >= 11) {
                float mx = vv[0];
#pragma unroll
                for (int o = 1; o < 20; ++o) mx = fmaxf(mx, vv[o]);
                float e[20], ssum = 0.0f;
#pragma unroll
                for (int o = 0; o < 20; ++o) { e[o] = __expf(vv[o] - mx); ssum += e[o]; }
                float inv = 1.0f / ssum;
#pragma unroll
                for (int o = 0; o < 20; ++o) ac[o] += e[o] * inv;
            }
        }
#pragma unroll
        for (int o = 0; o < 20; ++o) pacc[c][o] = ac[o];
    }
    __syncthreads();

    // phase 4: reduce
    if (tid < 160) {
        int o = tid >> 3, g = tid & 7;
        float s = 0.0f;
        for (int c = g * 25; c < g * 25 + 25; ++c) s += pacc[c][o];
        part[g][o] = s;
    }
    __syncthreads();
    if (tid < 20) {
        float s = 0.0f;
#pragma unroll
        for (int g = 0; g < 8; ++g) s += part[g][tid];
        out[(size_t)b * 20 + tid] = s;
    }
}

// ---------------------------------------------------------------------------
extern "C" void kernel_launch(void* const* d_in, const int* in_sizes, int n_in,
                              void* d_out, int out_size, void* d_ws, size_t ws_size,
                              hipStream_t stream) {
    const float* x   = (const float*)d_in[0];
    const float* W_h = (const float*)d_in[1];
    const float* b_h = (const float*)d_in[2];
    const float* W_r = (const float*)d_in[3];
    const float* b_r = (const float*)d_in[4];
    const float* tau = (const float*)d_in[5];

    unsigned short* wfrag = (unsigned short*)d_ws;
    float* out = (float*)d_out;

    wprep<<<22, 256, 0, stream>>>(W_h, wfrag);
    fused<<<B_, 512, 0, stream>>>(x, wfrag, b_h, W_r, b_r, tau, out);
}